// Round 6
// baseline (495.499 us; speedup 1.0000x reference)
//
#include <hip/hip_runtime.h>
#include <cstdint>

#define S_LEN   1024
#define D_DIM   512
#define H_HEADS 8
#define B_BATCH 4
#define NEGV    -1000000000.0f

typedef __bf16 bf16;
typedef __bf16 bf16x8 __attribute__((ext_vector_type(8)));
typedef __bf16 bf16x4 __attribute__((ext_vector_type(4)));
typedef float  f32x4  __attribute__((ext_vector_type(4)));

// async global->LDS, 16B per lane (wave-uniform LDS base + lane*16 semantics)
#define GLL16(gp, lp) __builtin_amdgcn_global_load_lds( \
    (const __attribute__((address_space(1))) void*)(gp), \
    (__attribute__((address_space(3))) void*)(lp), 16, 0, 0)

// counted vmcnt wait (T4) — literal N, memory clobber so LDS ops can't cross
#define VMW(N) asm volatile("s_waitcnt vmcnt(" #N ")" ::: "memory")
// raw barrier with compiler memory fence (no vmcnt drain)
#define BARM() do { asm volatile("" ::: "memory"); \
                    __builtin_amdgcn_s_barrier();  \
                    asm volatile("" ::: "memory"); } while (0)

// ---------------------------------------------------------------------------
// 256x256 8-wave pipelined GEMM, C = A @ B^T (+bias). BK=32, 4-deep LDS
// rotation, counted vmcnt (never 0 in main loop), frag-packed lane-linear LDS
// (bank-conflict-free ds_read_b128), ONE barrier per K-tile, setprio around
// the MFMA cluster, bijective XCD-chunked block swizzle.
// Requires M%256==0, N%256==0, K%32==0, K>=128.
// h-major layouts: head index h = n>>9 ranges over [0,9) (head 8 = p-branch).
// MODE 1: bf16 [h,b,s,d] out (+bias/bias2 by z)   (proj Q,K incl. p)
// MODE 2: bf16 [h,b,d,s] transposed out (+bias)   (proj V -> Vt incl. p)
// MODE 3: f32 natural out                          (PV out)
// MODE 4: bf16 scores out: v*scale, masked; z>=32 uses maskp (p-branch)
// ---------------------------------------------------------------------------
template<int MODE>
__global__ __launch_bounds__(512, 2) void gemm256_bt(
    const bf16* __restrict__ A, const bf16* __restrict__ B,
    void* __restrict__ Cout, const float* __restrict__ bias,
    const float* __restrict__ bias2, const int* __restrict__ mask,
    const int* __restrict__ maskp,
    int N, int K, long zsA, long zsB, long zsC, float scale)
{
  // T1: bijective XCD-chunked swizzle over the flattened grid (m204)
  const int gx = gridDim.x, gy = gridDim.y;
  const int nwg = gx * gy * gridDim.z;
  int bid = blockIdx.x + gx * (blockIdx.y + gy * blockIdx.z);
  {
    const int q = nwg >> 3, r = nwg & 7;
    const int xcd = bid & 7, idx = bid >> 3;
    bid = (xcd < r ? xcd * (q + 1) : r * (q + 1) + (xcd - r) * q) + idx;
  }
  const int bx = bid % gx;
  const int by = (bid / gx) % gy;
  const int z  = bid / (gx * gy);

  A += (long)z * zsA;
  B += (long)z * zsB;
  const int bm0 = bx * 256;
  const int bn0 = by * 256;

  // 4 rotating buffers; per buffer: A frags [0:8192), B frags [8192:16384)
  // (each 128-row half = 8 frags x 512 elems; frag = 1KiB lane-linear block)
  __shared__ __attribute__((aligned(16))) bf16 LDS[4 * 16384];  // 128 KiB

  const int tid  = threadIdx.x;
  const int wid  = tid >> 6;
  const int lane = tid & 63;
  const int wr = wid >> 2;        // 0..1: wave M-half
  const int wc = wid & 3;         // 0..3: wave N-quarter

  // staging source (pre-permuted per-lane so LDS lands lane-linear):
  // lane l stages (row = l&15, k-chunk = l>>4) of frag `wid` of each half
  const long arow = (long)(bm0 + wid * 16 + (lane & 15)) * K + ((lane >> 4) * 8);
  const long brow = (long)(bn0 + wid * 16 + (lane & 15)) * K + ((lane >> 4) * 8);
  const long rstep = 128L * (long)K;   // +128 rows (second half)

  auto stageA = [&](int tt) {          // 2 per-wave gloads (A half0, half1)
    bf16* d = LDS + (tt & 3) * 16384 + wid * 512;
    const bf16* g = A + arow + (long)tt * 32;
    GLL16(g, d);
    GLL16(g + rstep, d + 4096);
  };
  auto stageB = [&](int tt) {          // 2 per-wave gloads (B half0, half1)
    bf16* d = LDS + (tt & 3) * 16384 + 8192 + wid * 512;
    const bf16* g = B + brow + (long)tt * 32;
    GLL16(g, d);
    GLL16(g + rstep, d + 4096);
  };

  f32x4 acc[8][4] = {};
  const int NT = K >> 5;               // K-tiles of 32

  // prologue: stage tiles 0,1,2 (12 per-wave loads); retire tile 0 (oldest 4)
  stageA(0); stageB(0);
  stageA(1); stageB(1);
  stageA(2); stageB(2);
  VMW(8);
  BARM();

  for (int t = 0; t < NT; ++t) {
    const bf16* bufp = LDS + (t & 3) * 16384;
    const bf16* ap = bufp + wr * 4096 + lane * 8;          // A frags, own half
    const bf16* bp = bufp + 8192 + wc * 2048 + lane * 8;   // B frags, own 64

    // stage tile t+3 into buf[(t-1)&3] (all waves done reading it: gate t-1)
    if (t + 3 < NT) { stageA(t + 3); stageB(t + 3); }

    // read all 12 frags, one 32-MFMA cluster; compiler interleaves lgkmcnt
    bf16x8 a0[4], a1[4], bb[4];
#pragma unroll
    for (int i = 0; i < 4; ++i) a0[i] = *(const bf16x8*)(ap + i * 512);
#pragma unroll
    for (int i = 0; i < 4; ++i) bb[i] = *(const bf16x8*)(bp + i * 512);
#pragma unroll
    for (int i = 0; i < 4; ++i) a1[i] = *(const bf16x8*)(ap + (4 + i) * 512);

    __builtin_amdgcn_s_setprio(1);
#pragma unroll
    for (int mi = 0; mi < 4; ++mi)
#pragma unroll
      for (int ni = 0; ni < 4; ++ni)
        acc[mi][ni] = __builtin_amdgcn_mfma_f32_16x16x32_bf16(
            a0[mi], bb[ni], acc[mi][ni], 0, 0, 0);
#pragma unroll
    for (int mi = 0; mi < 4; ++mi)
#pragma unroll
      for (int ni = 0; ni < 4; ++ni)
        acc[4 + mi][ni] = __builtin_amdgcn_mfma_f32_16x16x32_bf16(
            a1[mi], bb[ni], acc[4 + mi][ni], 0, 0, 0);
    __builtin_amdgcn_s_setprio(0);

    // gate: after barrier, tile t+1 must be resident for ALL waves.
    // per-wave outstanding here: {t+1,t+2,t+3} x4 -> vmcnt(8) retires t+1.
    if (t <= NT - 4)      VMW(8);
    else if (t == NT - 3) VMW(4);
    else if (t == NT - 2) VMW(0);
    BARM();
  }

  // epilogue: C/D layout col = lane&15, row = (lane>>4)*4 + reg (m89)
  const int r0 = (lane >> 4) << 2;
  const int cn = lane & 15;

#pragma unroll
  for (int mi = 0; mi < 8; ++mi) {
#pragma unroll
    for (int ni = 0; ni < 4; ++ni) {
      const int n = bn0 + wc * 64 + ni * 16 + cn;
      float bv = 0.f;
      if constexpr (MODE != 4) {
        const float* bp2 = (z == 1 && bias2) ? bias2 : bias;
        if (bp2) bv = bp2[n];
      }
      int mk = 1;
      if constexpr (MODE == 4) {
        const int* mp = (z >= 32 ? maskp : mask);   // z = h*4+b; b = z&3
        mk = mp[(z & 3) * S_LEN + n];
      }
#pragma unroll
      for (int r = 0; r < 4; ++r) {
        const int m = bm0 + wr * 128 + mi * 16 + r0 + r;
        float v = acc[mi][ni][r];
        if constexpr (MODE == 1) {
          long o = (long)z * zsC +
                   (((long)(n >> 9) * B_BATCH + (m >> 10)) * S_LEN + (m & (S_LEN - 1))) * D_DIM
                   + (n & (D_DIM - 1));
          ((bf16*)Cout)[o] = (bf16)(v + bv);
        } else if constexpr (MODE == 2) {
          long o = (long)z * zsC +
                   (((long)(n >> 9) * B_BATCH + (m >> 10)) * D_DIM + (n & (D_DIM - 1))) * S_LEN
                   + (m & (S_LEN - 1));
          ((bf16*)Cout)[o] = (bf16)(v + bv);
        } else if constexpr (MODE == 3) {
          ((float*)Cout)[(long)z * zsC + (long)m * N + n] = v + bv;
        } else {
          float sv = (mk == 0) ? NEGV : v * scale;
          ((bf16*)Cout)[(long)z * zsC + (long)m * N + n] = (bf16)sv;
        }
      }
    }
  }
}

// ---------------------------------------------------------------------------
// 128x128 m97-structure GEMM (proven) — used for the final Wo GEMM.
// MODE 3: f32 natural out (+optional bias)
// ---------------------------------------------------------------------------
template<int MODE>
__global__ __launch_bounds__(256) void gemm_bt(
    const bf16* __restrict__ A, const bf16* __restrict__ B,
    void* __restrict__ Cout, const float* __restrict__ bias,
    const float* __restrict__ bias2, const int* __restrict__ mask,
    int N, int K, long zsA, long zsB, long zsC, float scale, int Hh)
{
  const int z = blockIdx.z;
  A += (long)z * zsA;
  B += (long)z * zsB;

  const int bm0 = blockIdx.x * 128;
  const int bn0 = blockIdx.y * 128;

  __shared__ __attribute__((aligned(16))) bf16 As[128 * 32];
  __shared__ __attribute__((aligned(16))) bf16 Bs[128 * 32];

  const int tid  = threadIdx.x;
  const int wid  = tid >> 6;
  const int lane = tid & 63;
  const int wm = (wid >> 1) * 64;
  const int wn = (wid & 1) * 64;

  const int srow = tid >> 2;
  const int scol = (tid & 3) * 8;
  const bf16* gA0 = A + (long)(bm0 + srow) * K + scol;
  const bf16* gA1 = A + (long)(bm0 + 64 + srow) * K + scol;
  const bf16* gB0 = B + (long)(bn0 + srow) * K + scol;
  const bf16* gB1 = B + (long)(bn0 + 64 + srow) * K + scol;
  bf16* lA0 = As + tid * 8;
  bf16* lA1 = As + 2048 + tid * 8;
  bf16* lB0 = Bs + tid * 8;
  bf16* lB1 = Bs + 2048 + tid * 8;

  const int lrow = lane & 15;
  const int lk   = (lane >> 4) * 8;
  const bf16* fA = As + (wm + lrow) * 32 + lk;
  const bf16* fB = Bs + (wn + lrow) * 32 + lk;

  f32x4 acc[4][4] = {};

  for (int k0 = 0; k0 < K; k0 += 32) {
    GLL16(gA0 + k0, lA0);
    GLL16(gA1 + k0, lA1);
    GLL16(gB0 + k0, lB0);
    GLL16(gB1 + k0, lB1);
    __syncthreads();
    bf16x8 af[4], bfr[4];
#pragma unroll
    for (int i = 0; i < 4; ++i) af[i]  = *(const bf16x8*)(fA + i * 16 * 32);
#pragma unroll
    for (int i = 0; i < 4; ++i) bfr[i] = *(const bf16x8*)(fB + i * 16 * 32);
#pragma unroll
    for (int mi = 0; mi < 4; ++mi)
#pragma unroll
      for (int ni = 0; ni < 4; ++ni)
        acc[mi][ni] = __builtin_amdgcn_mfma_f32_16x16x32_bf16(
            af[mi], bfr[ni], acc[mi][ni], 0, 0, 0);
    __syncthreads();
  }

  const int r0 = (lane >> 4) << 2;
  const int cn = lane & 15;

#pragma unroll
  for (int mi = 0; mi < 4; ++mi) {
#pragma unroll
    for (int ni = 0; ni < 4; ++ni) {
      const int n = bn0 + wn + ni * 16 + cn;
      float bv = 0.f;
      const float* bp = (z == 1 && bias2) ? bias2 : bias;
      if (bp) bv = bp[n];
#pragma unroll
      for (int r = 0; r < 4; ++r) {
        const int m = bm0 + wm + mi * 16 + r0 + r;
        float v = acc[mi][ni][r];
        if constexpr (MODE == 3) {
          ((float*)Cout)[(long)z * zsC + (long)m * N + n] = v + bv;
        }
      }
    }
  }
  (void)mask; (void)scale; (void)Hh;
}

// ---------------------------------------------------------------------------
// row softmax in place over 1024 bf16 entries per row (fp32 math)
// ---------------------------------------------------------------------------
__global__ __launch_bounds__(256) void softmax_rows(bf16* __restrict__ buf)
{
  const long row = blockIdx.x;
  bf16* p = buf + row * S_LEN;
  const int tid = threadIdx.x;
  const int wid = tid >> 6, lane = tid & 63;
  bf16x4 raw = *(const bf16x4*)(p + tid * 4);
  float v[4];
#pragma unroll
  for (int j = 0; j < 4; ++j) v[j] = (float)raw[j];
  float mx = fmaxf(fmaxf(v[0], v[1]), fmaxf(v[2], v[3]));
  for (int m = 32; m; m >>= 1) mx = fmaxf(mx, __shfl_xor(mx, m, 64));
  __shared__ float red[4];
  if (lane == 0) red[wid] = mx;
  __syncthreads();
  mx = fmaxf(fmaxf(red[0], red[1]), fmaxf(red[2], red[3]));
  float e[4]; float s = 0.f;
#pragma unroll
  for (int j = 0; j < 4; ++j) { e[j] = __expf(v[j] - mx); s += e[j]; }
  for (int m = 32; m; m >>= 1) s += __shfl_xor(s, m, 64);
  __syncthreads();
  if (lane == 0) red[wid] = s;
  __syncthreads();
  s = red[0] + red[1] + red[2] + red[3];
  const float inv = 1.f / s;
  bf16x4 o;
#pragma unroll
  for (int j = 0; j < 4; ++j) o[j] = (bf16)(e[j] * inv);
  *(bf16x4*)(p + tid * 4) = o;
}

// ---------------------------------------------------------------------------
// per (b,s): dis_h = ||x_h - xp||^2, w = softmax(1/(dis+1e-9)),
// mixed = 0.8*sum_h w_h x_h + 0.2*xp
// X layout h-major [(h*4+b), s, d] fp32; XP = X + 32*ZSD ([b,s,d]).
// writes row (b*S+s) of MIX: [0:512]=hi, [512:1024]=lo, [1024:1536]=hi
// ---------------------------------------------------------------------------
__global__ __launch_bounds__(256) void combine_kernel(
    const float* __restrict__ X, const float* __restrict__ XP,
    bf16* __restrict__ MIX)
{
  const int m = blockIdx.x;            // b*S + s
  const int b = m >> 10;
  const int s = m & (S_LEN - 1);
  const int tid = threadIdx.x;
  const int wid = tid >> 6, lane = tid & 63;
  const float2 xp = *(const float2*)(XP + (long)m * D_DIM + tid * 2);
  float xv0[H_HEADS], xv1[H_HEADS], part[H_HEADS];
#pragma unroll
  for (int h = 0; h < H_HEADS; ++h) {
    const float* xrow = X + ((long)(h * B_BATCH + b) * S_LEN + s) * D_DIM;
    float2 t = *(const float2*)(xrow + tid * 2);
    xv0[h] = t.x; xv1[h] = t.y;
    float d0 = t.x - xp.x, d1 = t.y - xp.y;
    part[h] = d0 * d0 + d1 * d1;
  }
  __shared__ float red[4][H_HEADS];
#pragma unroll
  for (int h = 0; h < H_HEADS; ++h) {
    float v = part[h];
    for (int mm = 32; mm; mm >>= 1) v += __shfl_xor(v, mm, 64);
    if (lane == 0) red[wid][h] = v;
  }
  __syncthreads();
  float w[H_HEADS]; float mx = -1e30f;
#pragma unroll
  for (int h = 0; h < H_HEADS; ++h) {
    float dis = red[0][h] + red[1][h] + red[2][h] + red[3][h];
    w[h] = 1.f / (dis + 1e-9f);
    mx = fmaxf(mx, w[h]);
  }
  float ssum = 0.f;
#pragma unroll
  for (int h = 0; h < H_HEADS; ++h) { w[h] = __expf(w[h] - mx); ssum += w[h]; }
  const float inv = 1.f / ssum;
  float m0 = 0.f, m1 = 0.f;
#pragma unroll
  for (int h = 0; h < H_HEADS; ++h) { m0 += w[h] * xv0[h]; m1 += w[h] * xv1[h]; }
  m0 = 0.8f * m0 * inv + 0.2f * xp.x;
  m1 = 0.8f * m1 * inv + 0.2f * xp.y;
  const bf16 h0 = (bf16)m0, h1 = (bf16)m1;
  const bf16 l0 = (bf16)(m0 - (float)h0), l1 = (bf16)(m1 - (float)h1);
  bf16* orow = MIX + (long)m * 1536;
  orow[tid * 2]        = h0; orow[tid * 2 + 1]        = h1;
  orow[512 + tid * 2]  = l0; orow[512 + tid * 2 + 1]  = l1;
  orow[1024 + tid * 2] = h0; orow[1024 + tid * 2 + 1] = h1;
}

// fp32 -> bf16 convert, 3 tensors selected by blockIdx.z, 8 elems/thread
__global__ __launch_bounds__(256) void cvt3_kernel(
    const float* __restrict__ s0, const float* __restrict__ s1, const float* __restrict__ s2,
    bf16* __restrict__ d0, bf16* __restrict__ d1, bf16* __restrict__ d2)
{
  const float* s = blockIdx.z == 0 ? s0 : (blockIdx.z == 1 ? s1 : s2);
  bf16* d       = blockIdx.z == 0 ? d0 : (blockIdx.z == 1 ? d1 : d2);
  const long i = ((long)blockIdx.x * 256 + threadIdx.x) * 8;
  float4 a = *(const float4*)(s + i);
  float4 b = *(const float4*)(s + i + 4);
  bf16x8 o;
  o[0]=(bf16)a.x; o[1]=(bf16)a.y; o[2]=(bf16)a.z; o[3]=(bf16)a.w;
  o[4]=(bf16)b.x; o[5]=(bf16)b.y; o[6]=(bf16)b.z; o[7]=(bf16)b.w;
  *(bf16x8*)(d + i) = o;
}

// concat biases: out[0:4096] = main, out[4096:4608] = p-branch
__global__ __launch_bounds__(256) void concat_bias(
    const float* __restrict__ b0, const float* __restrict__ p0,
    const float* __restrict__ b1, const float* __restrict__ p1,
    const float* __restrict__ b2, const float* __restrict__ p2,
    float* __restrict__ o0, float* __restrict__ o1, float* __restrict__ o2)
{
  const int i = blockIdx.x * 256 + threadIdx.x;   // 0..4607
  const float* bb; const float* pp; float* oo;
  if (blockIdx.y == 0)      { bb = b0; pp = p0; oo = o0; }
  else if (blockIdx.y == 1) { bb = b1; pp = p1; oo = o1; }
  else                      { bb = b2; pp = p2; oo = o2; }
  oo[i] = (i < 4096) ? bb[i] : pp[i - 4096];
}

// transpose (R x C fp32) -> (C x R bf16)
// TRIPLE=0: plain transpose-convert, row stride R
// TRIPLE=1: row stride 3R; writes hi at +0, hi at +R, lo-residual at +2R
template<int TRIPLE>
__global__ __launch_bounds__(256) void transpose_cvt3(
    const float* __restrict__ s0, const float* __restrict__ s1, const float* __restrict__ s2,
    bf16* __restrict__ d0, bf16* __restrict__ d1, bf16* __restrict__ d2,
    int R, int C)
{
  const float* src = blockIdx.z == 0 ? s0 : (blockIdx.z == 1 ? s1 : s2);
  bf16* dst       = blockIdx.z == 0 ? d0 : (blockIdx.z == 1 ? d1 : d2);
  __shared__ float t[32][33];
  const int tc = threadIdx.x & 31;
  const int tr = threadIdx.x >> 5;
  const int c0 = blockIdx.x * 32, r0 = blockIdx.y * 32;
#pragma unroll
  for (int i = 0; i < 4; ++i)
    t[tr + 8 * i][tc] = src[(long)(r0 + tr + 8 * i) * C + c0 + tc];
  __syncthreads();
  const int RD = TRIPLE ? 3 * R : R;
#pragma unroll
  for (int i = 0; i < 4; ++i) {
    float v = t[tc][tr + 8 * i];
    long o = (long)(c0 + tr + 8 * i) * RD + r0 + tc;
    const bf16 hi = (bf16)v;
    dst[o] = hi;
    if (TRIPLE) {
      dst[o + R] = hi;
      dst[o + 2 * R] = (bf16)(v - (float)hi);
    }
  }
}

// ---------------------------------------------------------------------------
extern "C" void kernel_launch(void* const* d_in, const int* in_sizes, int n_in,
                              void* d_out, int out_size, void* d_ws, size_t ws_size,
                              hipStream_t stream) {
  const float* query  = (const float*)d_in[0];
  const float* key    = (const float*)d_in[1];
  const float* value  = (const float*)d_in[2];
  const int*   mask   = (const int*)d_in[3];
  const int*   mask_p = (const int*)d_in[4];
  const float* Wq  = (const float*)d_in[5];  const float* bq  = (const float*)d_in[6];
  const float* Wk  = (const float*)d_in[7];  const float* bk  = (const float*)d_in[8];
  const float* Wv  = (const float*)d_in[9];  const float* bv  = (const float*)d_in[10];
  const float* Wpq = (const float*)d_in[11]; const float* bpq = (const float*)d_in[12];
  const float* Wpk = (const float*)d_in[13]; const float* bpk = (const float*)d_in[14];
  const float* Wpv = (const float*)d_in[15]; const float* bpv = (const float*)d_in[16];
  const float* Wo  = (const float*)d_in[17]; const float* bo  = (const float*)d_in[18];

  char* ws = (char*)d_ws;
  size_t off = 0;
  auto alloc = [&](size_t bytes) -> void* {
    void* p = ws + off;
    off += (bytes + 255) & ~(size_t)255;
    return p;
  };
  const long BS   = (long)B_BATCH * S_LEN;        // 4096
  const long ZSD  = (long)S_LEN * D_DIM;          // 524288
  const long ZSS  = (long)S_LEN * S_LEN;          // 1048576
  const long SD   = BS * D_DIM;                   // 2097152
  const long DD   = (long)D_DIM * D_DIM;          // 262144
  const long WSTR = SD + DD;                      // 4608*512 (concat weight z-stride)
  const long HSD  = 9L * B_BATCH * ZSD;           // 18874368 (9-head h-major tensor)

  // --- workspace plan (~207 MiB of 256 MiB), h-major 9-head layouts ---
  // concatenated transposed weights: [W | Wp] per branch (z-stride WSTR)
  bf16* WQT  = (bf16*)alloc(SD * 2);
  bf16* WPQT = (bf16*)alloc(DD * 2);              // adjacent after WQT
  bf16* WKT  = (bf16*)alloc(SD * 2);
  bf16* WPKT = (bf16*)alloc(DD * 2);
  bf16* WVT  = (bf16*)alloc(SD * 2);
  bf16* WPVT = (bf16*)alloc(DD * 2);
  bf16* WOT3 = (bf16*)alloc(3 * DD * 2);
  float* BQ9 = (float*)alloc(4608 * 4);
  float* BK9 = (float*)alloc(4608 * 4);
  float* BV9 = (float*)alloc(4608 * 4);
  // bf16 inputs; dead after projections -> MIX aliases (12 MiB)
  bf16* XQ16 = (bf16*)alloc(SD * 2);              // adjacent XQ,XK (z-stride SD)
  bf16* XK16 = (bf16*)alloc(SD * 2);
  bf16* XV16 = (bf16*)alloc(SD * 2);
  bf16* MIX  = XQ16;                              // alias: 4096*1536*2 = 12 MiB
  // Q,K h-major [9][4][S][D]; dead after scores -> X (fp32 72 MiB) aliases
  bf16* Q16  = (bf16*)alloc(HSD * 2);             // adjacent Q16,K16 (z-stride HSD)
  bf16* K16  = (bf16*)alloc(HSD * 2);
  float* X   = (float*)Q16;                       // [36][S][D] f32 = 72 MiB exact
  float* XP  = X + 32 * ZSD;                      // h=8 block
  bf16* VT9  = (bf16*)alloc(HSD * 2);             // [9][4][D][S]
  bf16* SC   = (bf16*)alloc(36L * ZSS * 2);       // [36][S][S] (z>=32 = p-branch)
  (void)in_sizes; (void)n_in; (void)out_size;

  if (off > ws_size) return;  // clean diagnostic failure, never OOB

  const dim3 blk(256);
  const dim3 blk512(512);
  const float scale = 0.044194173824159216f;  // 1/sqrt(512)

  // 1. inputs -> bf16 ; biases -> concatenated
  cvt3_kernel<<<dim3(1024, 1, 3), blk, 0, stream>>>(query, key, value, XQ16, XK16, XV16);
  concat_bias<<<dim3(18, 3), blk, 0, stream>>>(bq, bpq, bk, bpk, bv, bpv, BQ9, BK9, BV9);
  // 2. weights -> transposed bf16 (concat layout via separate dest pointers)
  transpose_cvt3<0><<<dim3(128, 16, 3), blk, 0, stream>>>(Wq, Wk, Wv, WQT, WKT, WVT, 512, 4096);
  transpose_cvt3<0><<<dim3(16, 16, 3), blk, 0, stream>>>(Wpq, Wpk, Wpv, WPQT, WPKT, WPVT, 512, 512);
  transpose_cvt3<1><<<dim3(16, 16, 1), blk, 0, stream>>>(Wo, Wo, Wo, WOT3, WOT3, WOT3, 512, 512);

  // 3. projections incl. p-branch (M=4096, N=4608, head 8 = p)
  gemm256_bt<1><<<dim3(16, 18, 2), blk512, 0, stream>>>(XQ16, WQT, Q16, BQ9, BK9,
      nullptr, nullptr, 4608, 512, SD, WSTR, HSD, 1.f);
  gemm256_bt<2><<<dim3(16, 18, 1), blk512, 0, stream>>>(XV16, WVT, VT9, BV9, nullptr,
      nullptr, nullptr, 4608, 512, 0, 0, 0, 1.f);

  // 4. scores = QK^T * scale, masked; z = h*4+b, z in [0,36), z>=32 -> p
  gemm256_bt<4><<<dim3(4, 4, 36), blk512, 0, stream>>>(Q16, K16, SC, nullptr, nullptr,
      mask, mask_p, 1024, 512, ZSD, ZSD, ZSS, scale);

  // 5. softmax over all 36*1024 rows
  softmax_rows<<<dim3(36864), blk, 0, stream>>>(SC);

  // 6. x = P @ V (fp32, X aliases Q16/K16 — dead after scores)
  gemm256_bt<3><<<dim3(4, 2, 36), blk512, 0, stream>>>(SC, VT9, X, nullptr, nullptr,
      nullptr, nullptr, 512, 1024, ZSS, ZSD, ZSD, 1.f);

  // 7. dis / head softmax / mix -> [hi|lo|hi] rows (MIX aliases XQ/XK/XV)
  combine_kernel<<<dim3(4096), blk, 0, stream>>>(X, XP, MIX);

  // 8. out = [m_hi|m_lo|m_hi] @ [Wo_hi|Wo_hi|Wo_lo]^T + bo  (fp32 out)
  gemm_bt<3><<<dim3(32, 4, 1), blk, 0, stream>>>(MIX, WOT3, d_out, bo, nullptr, nullptr,
      512, 1536, 0, 0, 0, 1.f, 1);
}

// Round 8
// 492.236 us; speedup vs baseline: 1.0066x; 1.0066x over previous
//
#include <hip/hip_runtime.h>
#include <cstdint>

#define S_LEN   1024
#define D_DIM   512
#define H_HEADS 8
#define B_BATCH 4
#define NEGV    -1000000000.0f

typedef __bf16 bf16;
typedef __bf16 bf16x8 __attribute__((ext_vector_type(8)));
typedef __bf16 bf16x4 __attribute__((ext_vector_type(4)));
typedef float  f32x4  __attribute__((ext_vector_type(4)));

// async global->LDS, 16B per lane (wave-uniform LDS base + lane*16 semantics)
#define GLL16(gp, lp) __builtin_amdgcn_global_load_lds( \
    (const __attribute__((address_space(1))) void*)(gp), \
    (__attribute__((address_space(3))) void*)(lp), 16, 0, 0)

// counted vmcnt wait (T4) — literal N, memory clobber so LDS ops can't cross
#define VMW(N) asm volatile("s_waitcnt vmcnt(" #N ")" ::: "memory")
// raw barrier with compiler memory fence (no vmcnt drain)
#define BARM() do { asm volatile("" ::: "memory"); \
                    __builtin_amdgcn_s_barrier();  \
                    asm volatile("" ::: "memory"); } while (0)

// ---------------------------------------------------------------------------
// 256x256 8-wave GEMM, m201-template schedule: BK=64, 2-deep LDS double
// buffer (128 KiB), 4 phases/K-tile {stage half-tile -> ds_read subtile ->
// [VMW gate pre-barrier at ph1/ph3] -> barrier -> setprio(1) -> 16 MFMA ->
// setprio(0) -> barrier}.  GATE INVARIANT (race fix for r7): every VMW sits
// BEFORE a barrier; data staged for half-tile h is only ds_read AFTER a
// barrier whose preceding per-wave VMW retired h on ALL waves.
// Steady-state accounting (stages: A(t+1,0)@ph0 B(t+1,0)@ph1 A(t+1,1)@ph2
// B(t+1,1)@ph3): ph1-end outstanding {A(t,1),B(t,1),A(t+1,0),B(t+1,0)}=8
// -> VMW(4) retires kk1(t); ph3-end outstanding {A(t+1,0),B(t+1,0),
// A(t+1,1),B(t+1,1)}=8 -> VMW(4) retires kk0(t+1). Tail t=NT-1: VMW(0)@ph1.
// Requires M%256==0, N%256==0, K%64==0, K>=128.
// h-major layouts: head index h = n>>9 in [0,9) (head 8 = p-branch).
// MODE 1: bf16 [h,b,s,d] out (+bias/bias2 by z)   (proj Q,K incl. p)
// MODE 2: bf16 [h,b,d,s] transposed out (+bias)   (proj V -> Vt incl. p)
// MODE 3: f32 natural out                          (PV out)
// MODE 4: bf16 scores out: v*scale, masked; z>=32 uses maskp (p-branch)
// ---------------------------------------------------------------------------
template<int MODE>
__global__ __launch_bounds__(512, 2) void gemm256_bt(
    const bf16* __restrict__ A, const bf16* __restrict__ B,
    void* __restrict__ Cout, const float* __restrict__ bias,
    const float* __restrict__ bias2, const int* __restrict__ mask,
    const int* __restrict__ maskp,
    int N, int K, long zsA, long zsB, long zsC, float scale)
{
  // T1: bijective XCD-chunked swizzle over the flattened grid (m204)
  const int gx = gridDim.x, gy = gridDim.y;
  const int nwg = gx * gy * gridDim.z;
  int bid = blockIdx.x + gx * (blockIdx.y + gy * blockIdx.z);
  {
    const int q = nwg >> 3, r = nwg & 7;
    const int xcd = bid & 7, idx = bid >> 3;
    bid = (xcd < r ? xcd * (q + 1) : r * (q + 1) + (xcd - r) * q) + idx;
  }
  const int bx = bid % gx;
  const int by = (bid / gx) % gy;
  const int z  = bid / (gx * gy);

  A += (long)z * zsA;
  B += (long)z * zsB;
  const int bm0 = bx * 256;
  const int bn0 = by * 256;

  // 2 buffers x 32768 bf16 (64 KB each). Per buffer:
  //   A frags: [kk<<13 | rf*512), rf in 0..15 (16-row groups), kk in {0,1}
  //   B frags: +16384, same indexing. Frag = 1 KiB lane-linear block.
  __shared__ __attribute__((aligned(16))) bf16 LDS[2 * 32768];  // 128 KiB

  const int tid  = threadIdx.x;
  const int wid  = tid >> 6;
  const int lane = tid & 63;
  const int wr = wid >> 2;        // 0..1: wave M-half
  const int wc = wid & 3;         // 0..3: wave N-quarter

  // staging: wave wid stages frags {2*wid, 2*wid+1} of each 16-frag half-tile
  // frag f source: row = f*16 + (lane&15), col = t*64 + kk*32 + (lane>>4)*8
  const int frow = lane & 15;
  const int fcol = (lane >> 4) * 8;
  const bf16* gA0 = A + (long)(bm0 + (2 * wid) * 16 + frow) * K + fcol;
  const bf16* gA1 = A + (long)(bm0 + (2 * wid + 1) * 16 + frow) * K + fcol;
  const bf16* gB0 = B + (long)(bn0 + (2 * wid) * 16 + frow) * K + fcol;
  const bf16* gB1 = B + (long)(bn0 + (2 * wid + 1) * 16 + frow) * K + fcol;

  auto stgA = [&](int t, int kk) {   // stage A half-tile kk of tile t (2 gloads)
    bf16* d = LDS + ((t & 1) << 15) + (kk << 13) + (2 * wid) * 512;
    const long c = (long)t * 64 + kk * 32;
    GLL16(gA0 + c, d);
    GLL16(gA1 + c, d + 512);
  };
  auto stgB = [&](int t, int kk) {   // stage B half-tile kk of tile t (2 gloads)
    bf16* d = LDS + ((t & 1) << 15) + 16384 + (kk << 13) + (2 * wid) * 512;
    const long c = (long)t * 64 + kk * 32;
    GLL16(gB0 + c, d);
    GLL16(gB1 + c, d + 512);
  };
  // operand reads (lane-linear, conflict-free)
  auto rdA = [&](int buf, int kk, int mi) -> const bf16* {
    return LDS + (buf << 15) + (kk << 13) + (wr * 8 + mi) * 512 + lane * 8;
  };
  auto rdB = [&](int buf, int kk, int ni) -> const bf16* {
    return LDS + (buf << 15) + 16384 + (kk << 13) + (wc * 4 + ni) * 512 + lane * 8;
  };

  f32x4 acc[8][4] = {};
  const int NT = K >> 6;               // K-tiles of 64

  // prologue: stage all 4 half-tiles of tile 0; gate kk0 (all waves) pre-barrier
  stgA(0, 0); stgB(0, 0); stgA(0, 1); stgB(0, 1);
  VMW(4);                              // retire A(0,0)+B(0,0)
  BARM();

  for (int t = 0; t < NT; ++t) {
    const int buf = t & 1;
    const bool pf = (t + 1 < NT);
    bf16x8 af[4], bb[4];

    // ---- ph0: kk0 mi0-3 (kk0 gated at end of previous tile) --------------
    if (pf) stgA(t + 1, 0);
#pragma unroll
    for (int i = 0; i < 4; ++i) af[i] = *(const bf16x8*)rdA(buf, 0, i);
#pragma unroll
    for (int i = 0; i < 4; ++i) bb[i] = *(const bf16x8*)rdB(buf, 0, i);
    BARM();
    __builtin_amdgcn_s_setprio(1);
#pragma unroll
    for (int mi = 0; mi < 4; ++mi)
#pragma unroll
      for (int ni = 0; ni < 4; ++ni)
        acc[mi][ni] = __builtin_amdgcn_mfma_f32_16x16x32_bf16(
            af[mi], bb[ni], acc[mi][ni], 0, 0, 0);
    __builtin_amdgcn_s_setprio(0);
    BARM();

    // ---- ph1: kk0 mi4-7 (B regs reused); PRE-BARRIER gate for kk1 --------
    if (pf) stgB(t + 1, 0);
#pragma unroll
    for (int i = 0; i < 4; ++i) af[i] = *(const bf16x8*)rdA(buf, 0, 4 + i);
    if (pf) { VMW(4); } else { VMW(0); }   // retire A(t,1)+B(t,1) on all waves
    BARM();
    __builtin_amdgcn_s_setprio(1);
#pragma unroll
    for (int mi = 0; mi < 4; ++mi)
#pragma unroll
      for (int ni = 0; ni < 4; ++ni)
        acc[4 + mi][ni] = __builtin_amdgcn_mfma_f32_16x16x32_bf16(
            af[mi], bb[ni], acc[4 + mi][ni], 0, 0, 0);
    __builtin_amdgcn_s_setprio(0);
    BARM();

    // ---- ph2: kk1 mi0-3 (kk1 gated at ph1) -------------------------------
    if (pf) stgA(t + 1, 1);
#pragma unroll
    for (int i = 0; i < 4; ++i) af[i] = *(const bf16x8*)rdA(buf, 1, i);
#pragma unroll
    for (int i = 0; i < 4; ++i) bb[i] = *(const bf16x8*)rdB(buf, 1, i);
    BARM();
    __builtin_amdgcn_s_setprio(1);
#pragma unroll
    for (int mi = 0; mi < 4; ++mi)
#pragma unroll
      for (int ni = 0; ni < 4; ++ni)
        acc[mi][ni] = __builtin_amdgcn_mfma_f32_16x16x32_bf16(
            af[mi], bb[ni], acc[mi][ni], 0, 0, 0);
    __builtin_amdgcn_s_setprio(0);
    BARM();

    // ---- ph3: kk1 mi4-7 (B regs reused); PRE-BARRIER gate for next kk0 ---
    if (pf) stgB(t + 1, 1);
#pragma unroll
    for (int i = 0; i < 4; ++i) af[i] = *(const bf16x8*)rdA(buf, 1, 4 + i);
    if (pf) VMW(4);                        // retire A(t+1,0)+B(t+1,0)
    BARM();
    __builtin_amdgcn_s_setprio(1);
#pragma unroll
    for (int mi = 0; mi < 4; ++mi)
#pragma unroll
      for (int ni = 0; ni < 4; ++ni)
        acc[4 + mi][ni] = __builtin_amdgcn_mfma_f32_16x16x32_bf16(
            af[mi], bb[ni], acc[4 + mi][ni], 0, 0, 0);
    __builtin_amdgcn_s_setprio(0);
    BARM();
  }

  // epilogue: C/D layout col = lane&15, row = (lane>>4)*4 + reg (m89)
  const int r0 = (lane >> 4) << 2;
  const int cn = lane & 15;

#pragma unroll
  for (int mi = 0; mi < 8; ++mi) {
#pragma unroll
    for (int ni = 0; ni < 4; ++ni) {
      const int n = bn0 + wc * 64 + ni * 16 + cn;
      float bv = 0.f;
      if constexpr (MODE != 4) {
        const float* bp2 = (z == 1 && bias2) ? bias2 : bias;
        if (bp2) bv = bp2[n];
      }
      int mk = 1;
      if constexpr (MODE == 4) {
        const int* mp = (z >= 32 ? maskp : mask);   // z = h*4+b; b = z&3
        mk = mp[(z & 3) * S_LEN + n];
      }
#pragma unroll
      for (int r = 0; r < 4; ++r) {
        const int m = bm0 + wr * 128 + mi * 16 + r0 + r;
        float v = acc[mi][ni][r];
        if constexpr (MODE == 1) {
          long o = (long)z * zsC +
                   (((long)(n >> 9) * B_BATCH + (m >> 10)) * S_LEN + (m & (S_LEN - 1))) * D_DIM
                   + (n & (D_DIM - 1));
          ((bf16*)Cout)[o] = (bf16)(v + bv);
        } else if constexpr (MODE == 2) {
          long o = (long)z * zsC +
                   (((long)(n >> 9) * B_BATCH + (m >> 10)) * D_DIM + (n & (D_DIM - 1))) * S_LEN
                   + (m & (S_LEN - 1));
          ((bf16*)Cout)[o] = (bf16)(v + bv);
        } else if constexpr (MODE == 3) {
          ((float*)Cout)[(long)z * zsC + (long)m * N + n] = v + bv;
        } else {
          float sv = (mk == 0) ? NEGV : v * scale;
          ((bf16*)Cout)[(long)z * zsC + (long)m * N + n] = (bf16)sv;
        }
      }
    }
  }
}

// ---------------------------------------------------------------------------
// 128x128 m97-structure GEMM (proven) — used for the final Wo GEMM.
// MODE 3: f32 natural out (+optional bias)
// ---------------------------------------------------------------------------
template<int MODE>
__global__ __launch_bounds__(256) void gemm_bt(
    const bf16* __restrict__ A, const bf16* __restrict__ B,
    void* __restrict__ Cout, const float* __restrict__ bias,
    const float* __restrict__ bias2, const int* __restrict__ mask,
    int N, int K, long zsA, long zsB, long zsC, float scale, int Hh)
{
  const int z = blockIdx.z;
  A += (long)z * zsA;
  B += (long)z * zsB;

  const int bm0 = blockIdx.x * 128;
  const int bn0 = blockIdx.y * 128;

  __shared__ __attribute__((aligned(16))) bf16 As[128 * 32];
  __shared__ __attribute__((aligned(16))) bf16 Bs[128 * 32];

  const int tid  = threadIdx.x;
  const int wid  = tid >> 6;
  const int lane = tid & 63;
  const int wm = (wid >> 1) * 64;
  const int wn = (wid & 1) * 64;

  const int srow = tid >> 2;
  const int scol = (tid & 3) * 8;
  const bf16* gA0 = A + (long)(bm0 + srow) * K + scol;
  const bf16* gA1 = A + (long)(bm0 + 64 + srow) * K + scol;
  const bf16* gB0 = B + (long)(bn0 + srow) * K + scol;
  const bf16* gB1 = B + (long)(bn0 + 64 + srow) * K + scol;
  bf16* lA0 = As + tid * 8;
  bf16* lA1 = As + 2048 + tid * 8;
  bf16* lB0 = Bs + tid * 8;
  bf16* lB1 = Bs + 2048 + tid * 8;

  const int lrow = lane & 15;
  const int lk   = (lane >> 4) * 8;
  const bf16* fA = As + (wm + lrow) * 32 + lk;
  const bf16* fB = Bs + (wn + lrow) * 32 + lk;

  f32x4 acc[4][4] = {};

  for (int k0 = 0; k0 < K; k0 += 32) {
    GLL16(gA0 + k0, lA0);
    GLL16(gA1 + k0, lA1);
    GLL16(gB0 + k0, lB0);
    GLL16(gB1 + k0, lB1);
    __syncthreads();
    bf16x8 af[4], bfr[4];
#pragma unroll
    for (int i = 0; i < 4; ++i) af[i]  = *(const bf16x8*)(fA + i * 16 * 32);
#pragma unroll
    for (int i = 0; i < 4; ++i) bfr[i] = *(const bf16x8*)(fB + i * 16 * 32);
#pragma unroll
    for (int mi = 0; mi < 4; ++mi)
#pragma unroll
      for (int ni = 0; ni < 4; ++ni)
        acc[mi][ni] = __builtin_amdgcn_mfma_f32_16x16x32_bf16(
            af[mi], bfr[ni], acc[mi][ni], 0, 0, 0);
    __syncthreads();
  }

  const int r0 = (lane >> 4) << 2;
  const int cn = lane & 15;

#pragma unroll
  for (int mi = 0; mi < 4; ++mi) {
#pragma unroll
    for (int ni = 0; ni < 4; ++ni) {
      const int n = bn0 + wn + ni * 16 + cn;
      float bv = 0.f;
      const float* bp = (z == 1 && bias2) ? bias2 : bias;
      if (bp) bv = bp[n];
#pragma unroll
      for (int r = 0; r < 4; ++r) {
        const int m = bm0 + wm + mi * 16 + r0 + r;
        float v = acc[mi][ni][r];
        if constexpr (MODE == 3) {
          ((float*)Cout)[(long)z * zsC + (long)m * N + n] = v + bv;
        }
      }
    }
  }
  (void)mask; (void)scale; (void)Hh;
}

// ---------------------------------------------------------------------------
// row softmax in place over 1024 bf16 entries per row (fp32 math)
// ---------------------------------------------------------------------------
__global__ __launch_bounds__(256) void softmax_rows(bf16* __restrict__ buf)
{
  const long row = blockIdx.x;
  bf16* p = buf + row * S_LEN;
  const int tid = threadIdx.x;
  const int wid = tid >> 6, lane = tid & 63;
  bf16x4 raw = *(const bf16x4*)(p + tid * 4);
  float v[4];
#pragma unroll
  for (int j = 0; j < 4; ++j) v[j] = (float)raw[j];
  float mx = fmaxf(fmaxf(v[0], v[1]), fmaxf(v[2], v[3]));
  for (int m = 32; m; m >>= 1) mx = fmaxf(mx, __shfl_xor(mx, m, 64));
  __shared__ float red[4];
  if (lane == 0) red[wid] = mx;
  __syncthreads();
  mx = fmaxf(fmaxf(red[0], red[1]), fmaxf(red[2], red[3]));
  float e[4]; float s = 0.f;
#pragma unroll
  for (int j = 0; j < 4; ++j) { e[j] = __expf(v[j] - mx); s += e[j]; }
  for (int m = 32; m; m >>= 1) s += __shfl_xor(s, m, 64);
  __syncthreads();
  if (lane == 0) red[wid] = s;
  __syncthreads();
  s = red[0] + red[1] + red[2] + red[3];
  const float inv = 1.f / s;
  bf16x4 o;
#pragma unroll
  for (int j = 0; j < 4; ++j) o[j] = (bf16)(e[j] * inv);
  *(bf16x4*)(p + tid * 4) = o;
}

// ---------------------------------------------------------------------------
// per (b,s): dis_h = ||x_h - xp||^2, w = softmax(1/(dis+1e-9)),
// mixed = 0.8*sum_h w_h x_h + 0.2*xp
// X layout h-major [(h*4+b), s, d] fp32; XP = X + 32*ZSD ([b,s,d]).
// writes row (b*S+s) of MIX: [0:512]=hi, [512:1024]=lo, [1024:1536]=hi
// ---------------------------------------------------------------------------
__global__ __launch_bounds__(256) void combine_kernel(
    const float* __restrict__ X, const float* __restrict__ XP,
    bf16* __restrict__ MIX)
{
  const int m = blockIdx.x;            // b*S + s
  const int b = m >> 10;
  const int s = m & (S_LEN - 1);
  const int tid = threadIdx.x;
  const int wid = tid >> 6, lane = tid & 63;
  const float2 xp = *(const float2*)(XP + (long)m * D_DIM + tid * 2);
  float xv0[H_HEADS], xv1[H_HEADS], part[H_HEADS];
#pragma unroll
  for (int h = 0; h < H_HEADS; ++h) {
    const float* xrow = X + ((long)(h * B_BATCH + b) * S_LEN + s) * D_DIM;
    float2 t = *(const float2*)(xrow + tid * 2);
    xv0[h] = t.x; xv1[h] = t.y;
    float d0 = t.x - xp.x, d1 = t.y - xp.y;
    part[h] = d0 * d0 + d1 * d1;
  }
  __shared__ float red[4][H_HEADS];
#pragma unroll
  for (int h = 0; h < H_HEADS; ++h) {
    float v = part[h];
    for (int mm = 32; mm; mm >>= 1) v += __shfl_xor(v, mm, 64);
    if (lane == 0) red[wid][h] = v;
  }
  __syncthreads();
  float w[H_HEADS]; float mx = -1e30f;
#pragma unroll
  for (int h = 0; h < H_HEADS; ++h) {
    float dis = red[0][h] + red[1][h] + red[2][h] + red[3][h];
    w[h] = 1.f / (dis + 1e-9f);
    mx = fmaxf(mx, w[h]);
  }
  float ssum = 0.f;
#pragma unroll
  for (int h = 0; h < H_HEADS; ++h) { w[h] = __expf(w[h] - mx); ssum += w[h]; }
  const float inv = 1.f / ssum;
  float m0 = 0.f, m1 = 0.f;
#pragma unroll
  for (int h = 0; h < H_HEADS; ++h) { m0 += w[h] * xv0[h]; m1 += w[h] * xv1[h]; }
  m0 = 0.8f * m0 * inv + 0.2f * xp.x;
  m1 = 0.8f * m1 * inv + 0.2f * xp.y;
  const bf16 h0 = (bf16)m0, h1 = (bf16)m1;
  const bf16 l0 = (bf16)(m0 - (float)h0), l1 = (bf16)(m1 - (float)h1);
  bf16* orow = MIX + (long)m * 1536;
  orow[tid * 2]        = h0; orow[tid * 2 + 1]        = h1;
  orow[512 + tid * 2]  = l0; orow[512 + tid * 2 + 1]  = l1;
  orow[1024 + tid * 2] = h0; orow[1024 + tid * 2 + 1] = h1;
}

// fp32 -> bf16 convert, 3 tensors selected by blockIdx.z, 8 elems/thread
__global__ __launch_bounds__(256) void cvt3_kernel(
    const float* __restrict__ s0, const float* __restrict__ s1, const float* __restrict__ s2,
    bf16* __restrict__ d0, bf16* __restrict__ d1, bf16* __restrict__ d2)
{
  const float* s = blockIdx.z == 0 ? s0 : (blockIdx.z == 1 ? s1 : s2);
  bf16* d       = blockIdx.z == 0 ? d0 : (blockIdx.z == 1 ? d1 : d2);
  const long i = ((long)blockIdx.x * 256 + threadIdx.x) * 8;
  float4 a = *(const float4*)(s + i);
  float4 b = *(const float4*)(s + i + 4);
  bf16x8 o;
  o[0]=(bf16)a.x; o[1]=(bf16)a.y; o[2]=(bf16)a.z; o[3]=(bf16)a.w;
  o[4]=(bf16)b.x; o[5]=(bf16)b.y; o[6]=(bf16)b.z; o[7]=(bf16)b.w;
  *(bf16x8*)(d + i) = o;
}

// concat biases: out[0:4096] = main, out[4096:4608] = p-branch
__global__ __launch_bounds__(256) void concat_bias(
    const float* __restrict__ b0, const float* __restrict__ p0,
    const float* __restrict__ b1, const float* __restrict__ p1,
    const float* __restrict__ b2, const float* __restrict__ p2,
    float* __restrict__ o0, float* __restrict__ o1, float* __restrict__ o2)
{
  const int i = blockIdx.x * 256 + threadIdx.x;   // 0..4607
  const float* bb; const float* pp; float* oo;
  if (blockIdx.y == 0)      { bb = b0; pp = p0; oo = o0; }
  else if (blockIdx.y == 1) { bb = b1; pp = p1; oo = o1; }
  else                      { bb = b2; pp = p2; oo = o2; }
  oo[i] = (i < 4096) ? bb[i] : pp[i - 4096];
}

// transpose (R x C fp32) -> (C x R bf16)
// TRIPLE=0: plain transpose-convert, row stride R
// TRIPLE=1: row stride 3R; writes hi at +0, hi at +R, lo-residual at +2R
template<int TRIPLE>
__global__ __launch_bounds__(256) void transpose_cvt3(
    const float* __restrict__ s0, const float* __restrict__ s1, const float* __restrict__ s2,
    bf16* __restrict__ d0, bf16* __restrict__ d1, bf16* __restrict__ d2,
    int R, int C)
{
  const float* src = blockIdx.z == 0 ? s0 : (blockIdx.z == 1 ? s1 : s2);
  bf16* dst       = blockIdx.z == 0 ? d0 : (blockIdx.z == 1 ? d1 : d2);
  __shared__ float t[32][33];
  const int tc = threadIdx.x & 31;
  const int tr = threadIdx.x >> 5;
  const int c0 = blockIdx.x * 32, r0 = blockIdx.y * 32;
#pragma unroll
  for (int i = 0; i < 4; ++i)
    t[tr + 8 * i][tc] = src[(long)(r0 + tr + 8 * i) * C + c0 + tc];
  __syncthreads();
  const int RD = TRIPLE ? 3 * R : R;
#pragma unroll
  for (int i = 0; i < 4; ++i) {
    float v = t[tc][tr + 8 * i];
    long o = (long)(c0 + tr + 8 * i) * RD + r0 + tc;
    const bf16 hi = (bf16)v;
    dst[o] = hi;
    if (TRIPLE) {
      dst[o + R] = hi;
      dst[o + 2 * R] = (bf16)(v - (float)hi);
    }
  }
}

// ---------------------------------------------------------------------------
extern "C" void kernel_launch(void* const* d_in, const int* in_sizes, int n_in,
                              void* d_out, int out_size, void* d_ws, size_t ws_size,
                              hipStream_t stream) {
  const float* query  = (const float*)d_in[0];
  const float* key    = (const float*)d_in[1];
  const float* value  = (const float*)d_in[2];
  const int*   mask   = (const int*)d_in[3];
  const int*   mask_p = (const int*)d_in[4];
  const float* Wq  = (const float*)d_in[5];  const float* bq  = (const float*)d_in[6];
  const float* Wk  = (const float*)d_in[7];  const float* bk  = (const float*)d_in[8];
  const float* Wv  = (const float*)d_in[9];  const float* bv  = (const float*)d_in[10];
  const float* Wpq = (const float*)d_in[11]; const float* bpq = (const float*)d_in[12];
  const float* Wpk = (const float*)d_in[13]; const float* bpk = (const float*)d_in[14];
  const float* Wpv = (const float*)d_in[15]; const float* bpv = (const float*)d_in[16];
  const float* Wo  = (const float*)d_in[17]; const float* bo  = (const float*)d_in[18];

  char* ws = (char*)d_ws;
  size_t off = 0;
  auto alloc = [&](size_t bytes) -> void* {
    void* p = ws + off;
    off += (bytes + 255) & ~(size_t)255;
    return p;
  };
  const long BS   = (long)B_BATCH * S_LEN;        // 4096
  const long ZSD  = (long)S_LEN * D_DIM;          // 524288
  const long ZSS  = (long)S_LEN * S_LEN;          // 1048576
  const long SD   = BS * D_DIM;                   // 2097152
  const long DD   = (long)D_DIM * D_DIM;          // 262144
  const long WSTR = SD + DD;                      // 4608*512 (concat weight z-stride)
  const long HSD  = 9L * B_BATCH * ZSD;           // 18874368 (9-head h-major tensor)

  // --- workspace plan (~207 MiB of 256 MiB), h-major 9-head layouts ---
  // concatenated transposed weights: [W | Wp] per branch (z-stride WSTR)
  bf16* WQT  = (bf16*)alloc(SD * 2);
  bf16* WPQT = (bf16*)alloc(DD * 2);              // adjacent after WQT
  bf16* WKT  = (bf16*)alloc(SD * 2);
  bf16* WPKT = (bf16*)alloc(DD * 2);
  bf16* WVT  = (bf16*)alloc(SD * 2);
  bf16* WPVT = (bf16*)alloc(DD * 2);
  bf16* WOT3 = (bf16*)alloc(3 * DD * 2);
  float* BQ9 = (float*)alloc(4608 * 4);
  float* BK9 = (float*)alloc(4608 * 4);
  float* BV9 = (float*)alloc(4608 * 4);
  // bf16 inputs; dead after projections -> MIX aliases (12 MiB)
  bf16* XQ16 = (bf16*)alloc(SD * 2);              // adjacent XQ,XK (z-stride SD)
  bf16* XK16 = (bf16*)alloc(SD * 2);
  bf16* XV16 = (bf16*)alloc(SD * 2);
  bf16* MIX  = XQ16;                              // alias: 4096*1536*2 = 12 MiB
  // Q,K h-major [9][4][S][D]; dead after scores -> X (fp32 72 MiB) aliases
  bf16* Q16  = (bf16*)alloc(HSD * 2);             // adjacent Q16,K16 (z-stride HSD)
  bf16* K16  = (bf16*)alloc(HSD * 2);
  float* X   = (float*)Q16;                       // [36][S][D] f32 = 72 MiB exact
  float* XP  = X + 32 * ZSD;                      // h=8 block
  bf16* VT9  = (bf16*)alloc(HSD * 2);             // [9][4][D][S]
  bf16* SC   = (bf16*)alloc(36L * ZSS * 2);       // [36][S][S] (z>=32 = p-branch)
  (void)in_sizes; (void)n_in; (void)out_size;

  if (off > ws_size) return;  // clean diagnostic failure, never OOB

  const dim3 blk(256);
  const dim3 blk512(512);
  const float scale = 0.044194173824159216f;  // 1/sqrt(512)

  // 1. inputs -> bf16 ; biases -> concatenated
  cvt3_kernel<<<dim3(1024, 1, 3), blk, 0, stream>>>(query, key, value, XQ16, XK16, XV16);
  concat_bias<<<dim3(18, 3), blk, 0, stream>>>(bq, bpq, bk, bpk, bv, bpv, BQ9, BK9, BV9);
  // 2. weights -> transposed bf16 (concat layout via separate dest pointers)
  transpose_cvt3<0><<<dim3(128, 16, 3), blk, 0, stream>>>(Wq, Wk, Wv, WQT, WKT, WVT, 512, 4096);
  transpose_cvt3<0><<<dim3(16, 16, 3), blk, 0, stream>>>(Wpq, Wpk, Wpv, WPQT, WPKT, WPVT, 512, 512);
  transpose_cvt3<1><<<dim3(16, 16, 1), blk, 0, stream>>>(Wo, Wo, Wo, WOT3, WOT3, WOT3, 512, 512);

  // 3. projections incl. p-branch (M=4096, N=4608, head 8 = p)
  gemm256_bt<1><<<dim3(16, 18, 2), blk512, 0, stream>>>(XQ16, WQT, Q16, BQ9, BK9,
      nullptr, nullptr, 4608, 512, SD, WSTR, HSD, 1.f);
  gemm256_bt<2><<<dim3(16, 18, 1), blk512, 0, stream>>>(XV16, WVT, VT9, BV9, nullptr,
      nullptr, nullptr, 4608, 512, 0, 0, 0, 1.f);

  // 4. scores = QK^T * scale, masked; z = h*4+b, z in [0,36), z>=32 -> p
  gemm256_bt<4><<<dim3(4, 4, 36), blk512, 0, stream>>>(Q16, K16, SC, nullptr, nullptr,
      mask, mask_p, 1024, 512, ZSD, ZSD, ZSS, scale);

  // 5. softmax over all 36*1024 rows
  softmax_rows<<<dim3(36864), blk, 0, stream>>>(SC);

  // 6. x = P @ V (fp32, X aliases Q16/K16 — dead after scores)
  gemm256_bt<3><<<dim3(4, 2, 36), blk512, 0, stream>>>(SC, VT9, X, nullptr, nullptr,
      nullptr, nullptr, 512, 1024, ZSS, ZSD, ZSD, 1.f);

  // 7. dis / head softmax / mix -> [hi|lo|hi] rows (MIX aliases XQ/XK/XV)
  combine_kernel<<<dim3(4096), blk, 0, stream>>>(X, XP, MIX);

  // 8. out = [m_hi|m_lo|m_hi] @ [Wo_hi|Wo_hi|Wo_lo]^T + bo  (fp32 out)
  gemm_bt<3><<<dim3(32, 4, 1), blk, 0, stream>>>(MIX, WOT3, d_out, bo, nullptr, nullptr,
      512, 1536, 0, 0, 0, 1.f, 1);
}